// Round 5
// baseline (372.664 us; speedup 1.0000x reference)
//
#include <hip/hip_runtime.h>
#include <stdint.h>

// ForceGrid: 10M weighted particles -> 256^3 float grid.
//
// Round-10 structure (2 real passes, ZERO global atomics in the hot loop):
//   k0_init   : side_n = 0.                                    (tiny)
//   k3_direct : single pass over particles. LDS ring-stage per superbin
//               (1024 bins x 16-deep). Each (block,bin) owns a FIXED
//               72-pair segment: pairs[bin][blk][CAP]. After each
//               4096-particle tile (2 barriers), thread tid flushes bin
//               tid's full 8-pair chunks straight to
//               segbase + flushed (4 x 16B NT stores = one complete 64B
//               line) -- destination is pure arithmetic, NO gcur atomic,
//               NO build phase, NO worklist. Real counts -> cnt[bin][blk];
//               final partial chunk written as a full 64B line with stale
//               tail (ignored by K4 via cnt). Overflow -> side-list.
//   k4_direct : one block per superbin, 64KB LDS accumulate; 4 threads per
//               (blk) segment read dwordx4 (2 pairs) up to cnt; side-list
//               replay; coalesced NT store.
//
// Why: round-8/9 showed k3 stuck at ~91us with VALUBusy 13%, HBM 22%,
// prefetch+lgkm-barriers neutral. The unpriced cost was the build phase's
// cross-XCD atomicAdd(&gcur[bin],8): ~1.3M device-scope atomics hammering
// one 4KB array in barrier-aligned bursts from all 256 blocks. Fixed
// per-(block,bin) segments make destinations arithmetic.
//
// Numerics (bit-exact index math vs the XLA-folded reference; DO NOT change):
//   fi = fl32((p + 10.0f) * 12.75f)   // 12.75f == fl32(1/fl32(20/255))
//   i  = (int32)fl32(fi + 0.5f)       // trunc toward zero, NO FMA contraction

constexpr int GRID_N = 256;
constexpr int SB     = 1024;    // superbins; superbin = flat >> 14
constexpr int CELLS  = 16384;   // cells per superbin (64KB LDS in K4)
constexpr int NB     = 256;     // blocks for the scatter pass (1/CU)
constexpr int BT     = 1024;    // threads per block (== SB: thread owns bin)
constexpr int RING   = 16;      // staged pairs per bin (power of 2)
constexpr int RSTR   = 17;      // ring stride in uint2 (LDS bank spread)
constexpr uint32_t CAP = 72;    // pairs per (block,bin) segment (mult of 8)
                                // Poisson(39): P(>72) ~ 1e-7 per cell
constexpr uint32_t SIDE_CAP = 65536;   // global overflow records

typedef unsigned int u32x4 __attribute__((ext_vector_type(4)));
typedef float        f32x4 __attribute__((ext_vector_type(4)));

// Barrier with LDS-only drain: global loads/stores stay in flight.
#define BAR_LGKM() do { \
    asm volatile("s_waitcnt lgkmcnt(0)" ::: "memory"); \
    __builtin_amdgcn_s_barrier(); \
} while (0)

__device__ __forceinline__ int particle_flat(float px, float py, float pz) {
#pragma clang fp contract(off)
    float fix = (px + 10.0f) * 12.75f;
    float fiy = (py + 10.0f) * 12.75f;
    float fiz = (pz + 10.0f) * 12.75f;
    int ix = (int)(fix + 0.5f);
    int iy = (int)(fiy + 0.5f);
    int iz = (int)(fiz + 0.5f);
    bool in = (ix >= 0) & (ix < GRID_N) &
              (iy >= 0) & (iy < GRID_N) &
              (iz >= 0) & (iz < GRID_N);
    return in ? ((ix << 16) | (iy << 8) | iz) : -1;
}

// ---- k0: init side-list counter --------------------------------------------
__global__ __launch_bounds__(64) void k0_init(uint32_t* __restrict__ side_n)
{
    if (threadIdx.x == 0) *side_n = 0;
}

// ---- k3: single-pass staged scatter, fixed segments, owner-thread flush -----
__global__ __launch_bounds__(BT, 1) void k3_direct(
    const float* __restrict__ pos, const float* __restrict__ wgt,
    uint2* __restrict__ pairs, uint32_t* __restrict__ cnt,
    uint2* __restrict__ side, uint32_t* __restrict__ side_n, int n)
{
    __shared__ uint2    stg[SB][RSTR];     // ring storage (slots 0..15 used)
    __shared__ uint32_t s_total[SB];       // arrival count per bin (LDS atomic)
    __shared__ uint32_t s_flushed[SB];     // flushed count per bin (mult. of 8)

    const int tid = threadIdx.x;
    const int blk = blockIdx.x;

    s_total[tid]   = 0;
    s_flushed[tid] = 0;
    __syncthreads();

    // this thread's (bin=tid, blk) segment base in pairs[]
    const size_t segbase = ((size_t)tid * NB + blk) * CAP;

    const float4* p4 = (const float4*)pos;
    const float4* w4 = (const float4*)wgt;
    int ngroups = n >> 2;
    int G = NB * BT;
    int iters = (ngroups + G - 1) / G;     // uniform across all threads/blocks

    // tile-0 load
    int g = blk * BT + tid;
    bool valid = g < ngroups;
    float4 a = {}, b = {}, c = {}, w = {};
    if (valid) {
        a = p4[(size_t)g * 3 + 0];
        b = p4[(size_t)g * 3 + 1];
        c = p4[(size_t)g * 3 + 2];
        w = w4[g];
    }

    for (int it = 0; it < iters; ++it) {
        // ---- prefetch next tile into registers ----
        int gn = g + G;
        bool v2 = (it + 1 < iters) && (gn < ngroups);
        float4 a2 = {}, b2 = {}, c2 = {}, w2 = {};
        if (v2) {
            a2 = p4[(size_t)gn * 3 + 0];
            b2 = p4[(size_t)gn * 3 + 1];
            c2 = p4[(size_t)gn * 3 + 2];
            w2 = w4[gn];
        }

        // ---- stage current tile ----
        if (valid) {
            int   f[4]  = { particle_flat(a.x, a.y, a.z), particle_flat(a.w, b.x, b.y),
                            particle_flat(b.z, b.w, c.x), particle_flat(c.y, c.z, c.w) };
            float ww[4] = { w.x, w.y, w.z, w.w };
#pragma unroll
            for (int k = 0; k < 4; ++k) {
                int fk = f[k];
                if (fk >= 0) {
                    uint32_t bin  = (uint32_t)fk >> 14;
                    uint32_t slot = atomicAdd(&s_total[bin], 1u);
                    if (slot - s_flushed[bin] < (uint32_t)RING) {
                        stg[bin][slot & (RING - 1)] =
                            make_uint2((uint32_t)fk & (CELLS - 1), __float_as_uint(ww[k]));
                    } else {
                        // ring full: give the slot back (keeps staged slots dense),
                        // park the record in the global side-list.
                        atomicSub(&s_total[bin], 1u);
                        uint32_t si = atomicAdd(side_n, 1u);
                        if (si < SIDE_CAP)
                            side[si] = make_uint2((uint32_t)fk, __float_as_uint(ww[k]));
                    }
                }
            }
        }
        BAR_LGKM();
        // ---- flush: thread tid drains bin tid's full chunks ----
        {
            uint32_t t_ = s_total[tid];
            uint32_t fl = s_flushed[tid];
            while (t_ - fl >= 8u) {
                uint32_t o = fl & (RING - 1);          // 0 or 8 (contiguous)
                if (fl < CAP) {
                    uint2 v0 = stg[tid][o + 0], v1 = stg[tid][o + 1];
                    uint2 v2r = stg[tid][o + 2], v3 = stg[tid][o + 3];
                    uint2 v4 = stg[tid][o + 4], v5 = stg[tid][o + 5];
                    uint2 v6 = stg[tid][o + 6], v7 = stg[tid][o + 7];
                    u32x4 q0 = { v0.x, v0.y, v1.x, v1.y };
                    u32x4 q1 = { v2r.x, v2r.y, v3.x, v3.y };
                    u32x4 q2 = { v4.x, v4.y, v5.x, v5.y };
                    u32x4 q3 = { v6.x, v6.y, v7.x, v7.y };
                    u32x4* dst = (u32x4*)&pairs[segbase + fl];
                    __builtin_nontemporal_store(q0, dst + 0);
                    __builtin_nontemporal_store(q1, dst + 1);
                    __builtin_nontemporal_store(q2, dst + 2);
                    __builtin_nontemporal_store(q3, dst + 3);
                } else {
                    // segment full (P ~ 1e-7 per cell): spill chunk to side-list
                    for (int j = 0; j < 8; ++j) {
                        uint2 v = stg[tid][o + j];
                        uint32_t si = atomicAdd(side_n, 1u);
                        if (si < SIDE_CAP)
                            side[si] = make_uint2(((uint32_t)tid << 14) | v.x, v.y);
                    }
                }
                fl += 8u;
            }
            s_flushed[tid] = fl;
        }
        BAR_LGKM();

        a = a2; b = b2; c = c2; w = w2; valid = v2; g = gn;
    }

    // global tail (n % 4 particles): straight to side-list, block 0 only
    if (blk == 0 && tid == 0) {
        for (int p = n & ~3; p < n; ++p) {
            int f = particle_flat(pos[3 * p], pos[3 * p + 1], pos[3 * p + 2]);
            if (f >= 0) {
                uint32_t si = atomicAdd(side_n, 1u);
                if (si < SIDE_CAP)
                    side[si] = make_uint2((uint32_t)f, __float_as_uint(wgt[p]));
            }
        }
    }

    // epilogue: at most one partial chunk per bin remains (<8 pending).
    // Write it as a FULL 64B line: the stale tail slots are ignored by K4
    // (it reads only cnt entries). No zero-padding pass needed.
    {
        uint32_t t_ = s_total[tid];
        uint32_t fl = s_flushed[tid];
        if (t_ > fl) {
            uint32_t o = fl & (RING - 1);
            if (fl < CAP) {
                uint2 v0 = stg[tid][o + 0], v1 = stg[tid][o + 1];
                uint2 v2r = stg[tid][o + 2], v3 = stg[tid][o + 3];
                uint2 v4 = stg[tid][o + 4], v5 = stg[tid][o + 5];
                uint2 v6 = stg[tid][o + 6], v7 = stg[tid][o + 7];
                u32x4 q0 = { v0.x, v0.y, v1.x, v1.y };
                u32x4 q1 = { v2r.x, v2r.y, v3.x, v3.y };
                u32x4 q2 = { v4.x, v4.y, v5.x, v5.y };
                u32x4 q3 = { v6.x, v6.y, v7.x, v7.y };
                u32x4* dst = (u32x4*)&pairs[segbase + fl];
                __builtin_nontemporal_store(q0, dst + 0);
                __builtin_nontemporal_store(q1, dst + 1);
                __builtin_nontemporal_store(q2, dst + 2);
                __builtin_nontemporal_store(q3, dst + 3);
            } else {
                for (uint32_t j = 0; j < t_ - fl; ++j) {
                    uint2 v = stg[tid][(o + j) & (RING - 1)];
                    uint32_t si = atomicAdd(side_n, 1u);
                    if (si < SIDE_CAP)
                        side[si] = make_uint2(((uint32_t)tid << 14) | v.x, v.y);
                }
            }
        }
        // pairs durably written for indices < min(t_, CAP)
        cnt[(size_t)tid * NB + blk] = t_ < CAP ? t_ : CAP;
    }
}

// ---- k4: one block per superbin — 64KB LDS accumulate over 256 segments -----
__global__ __launch_bounds__(BT) void k4_direct(const uint2* __restrict__ pairs,
                                                const uint32_t* __restrict__ cnt,
                                                const uint2* __restrict__ side,
                                                const uint32_t* __restrict__ side_n,
                                                float* __restrict__ grid)
{
    __shared__ float    acc[CELLS];   // 64KB — 2 blocks/CU
    __shared__ uint32_t s_cnt[NB];

    int b = blockIdx.x;
    if (threadIdx.x < NB) s_cnt[threadIdx.x] = cnt[(size_t)b * NB + threadIdx.x];
    for (int i = threadIdx.x; i < CELLS; i += BT) acc[i] = 0.0f;
    __syncthreads();

    // 4 threads per (blk) segment; each reads dwordx4 = 2 pairs per step
    {
        int seg = threadIdx.x >> 2;            // 0..255
        int q   = threadIdx.x & 3;
        uint32_t c = s_cnt[seg];
        const u32x4* base = (const u32x4*)&pairs[((size_t)b * NB + seg) * CAP];
        for (uint32_t p0 = (uint32_t)q * 2u; p0 < c; p0 += 8u) {
            u32x4 v = __builtin_nontemporal_load(base + (p0 >> 1));
            atomicAdd(&acc[v.x & (CELLS - 1)], __uint_as_float(v.y));
            if (p0 + 1u < c)
                atomicAdd(&acc[v.z & (CELLS - 1)], __uint_as_float(v.w));
        }
    }
    // side-list replay (normally ~0-1e3 entries; each block filters its own)
    uint32_t ns = *side_n;
    if (ns > SIDE_CAP) ns = SIDE_CAP;
    for (uint32_t i = threadIdx.x; i < ns; i += BT) {
        uint2 sv = side[i];
        if ((int)(sv.x >> 14) == b)
            atomicAdd(&acc[sv.x & (CELLS - 1)], __uint_as_float(sv.y));
    }
    __syncthreads();

    f32x4* out4 = (f32x4*)(grid + (size_t)b * CELLS);
    const f32x4* a4 = (const f32x4*)acc;
    for (int i = threadIdx.x; i < CELLS / 4; i += BT)
        __builtin_nontemporal_store(a4[i], &out4[i]);
}

// ============================================================================
// tier-2 fallback: hist + scans + direct scatter (~82 MB ws)
// ============================================================================
__global__ __launch_bounds__(BT) void k1_hist(const float* __restrict__ pos,
                                              uint32_t* __restrict__ hist,
                                              int n)
{
    __shared__ uint32_t h[SB];
    for (int i = threadIdx.x; i < SB; i += BT) h[i] = 0;
    __syncthreads();

    const float4* p4 = (const float4*)pos;
    int ngroups = n >> 2;
    int G = gridDim.x * BT;
    for (int g = blockIdx.x * BT + threadIdx.x; g < ngroups; g += G) {
        float4 a = p4[(size_t)g * 3 + 0];
        float4 b = p4[(size_t)g * 3 + 1];
        float4 c = p4[(size_t)g * 3 + 2];
        int f0 = particle_flat(a.x, a.y, a.z);
        int f1 = particle_flat(a.w, b.x, b.y);
        int f2 = particle_flat(b.z, b.w, c.x);
        int f3 = particle_flat(c.y, c.z, c.w);
        if (f0 >= 0) atomicAdd(&h[f0 >> 14], 1u);
        if (f1 >= 0) atomicAdd(&h[f1 >> 14], 1u);
        if (f2 >= 0) atomicAdd(&h[f2 >> 14], 1u);
        if (f3 >= 0) atomicAdd(&h[f3 >> 14], 1u);
    }
    if (blockIdx.x == 0 && threadIdx.x == 0) {
        for (int p = n & ~3; p < n; ++p) {
            int f = particle_flat(pos[3 * p], pos[3 * p + 1], pos[3 * p + 2]);
            if (f >= 0) atomicAdd(&h[f >> 14], 1u);
        }
    }
    __syncthreads();
    uint32_t* out = hist + (size_t)blockIdx.x * SB;
    for (int i = threadIdx.x; i < SB; i += BT) out[i] = h[i];
}

__global__ __launch_bounds__(128) void k2a_colscan(const uint32_t* __restrict__ hist,
                                                   uint32_t* __restrict__ offs,
                                                   uint32_t* __restrict__ totals)
{
    int b = blockIdx.x * 128 + threadIdx.x;
    uint32_t run = 0;
    for (int blk = 0; blk < NB; blk += 8) {
        uint32_t v[8];
#pragma unroll
        for (int j = 0; j < 8; ++j)
            v[j] = hist[(size_t)(blk + j) * SB + b];
#pragma unroll
        for (int j = 0; j < 8; ++j) {
            offs[(size_t)(blk + j) * SB + b] = run;
            run += v[j];
        }
    }
    totals[b] = run;
}

__global__ __launch_bounds__(256) void k2b_scan(const uint32_t* __restrict__ totals,
                                                uint32_t* __restrict__ base)
{
    __shared__ uint32_t part[256];
    int t = threadIdx.x;
    uint32_t local[4];
    uint32_t s = 0;
#pragma unroll
    for (int j = 0; j < 4; ++j) { local[j] = totals[t * 4 + j]; s += local[j]; }
    part[t] = s;
    __syncthreads();
    if (t == 0) {
        uint32_t run = 0;
        for (int i = 0; i < 256; ++i) { uint32_t tmp = part[i]; part[i] = run; run += tmp; }
    }
    __syncthreads();
    uint32_t run = part[t];
#pragma unroll
    for (int j = 0; j < 4; ++j) { base[t * 4 + j] = run; run += local[j]; }
    if (t == 255) base[SB] = run;
}

__global__ __launch_bounds__(BT) void k3_scatter(const float* __restrict__ pos,
                                                 const float* __restrict__ wgt,
                                                 const uint32_t* __restrict__ offs,
                                                 const uint32_t* __restrict__ base,
                                                 uint2* __restrict__ pairs,
                                                 int n)
{
    __shared__ uint32_t cur[SB];
    for (int i = threadIdx.x; i < SB; i += BT)
        cur[i] = base[i] + offs[(size_t)blockIdx.x * SB + i];
    __syncthreads();

    const float4* p4 = (const float4*)pos;
    const float4* w4 = (const float4*)wgt;
    int ngroups = n >> 2;
    int G = gridDim.x * BT;
    for (int g = blockIdx.x * BT + threadIdx.x; g < ngroups; g += G) {
        float4 a = p4[(size_t)g * 3 + 0];
        float4 b = p4[(size_t)g * 3 + 1];
        float4 c = p4[(size_t)g * 3 + 2];
        float4 w = w4[g];
        int   f[4]  = { particle_flat(a.x, a.y, a.z), particle_flat(a.w, b.x, b.y),
                        particle_flat(b.z, b.w, c.x), particle_flat(c.y, c.z, c.w) };
        float ww[4] = { w.x, w.y, w.z, w.w };
#pragma unroll
        for (int k = 0; k < 4; ++k) {
            if (f[k] >= 0) {
                uint32_t slot = atomicAdd(&cur[f[k] >> 14], 1u);
                pairs[slot] = make_uint2((uint32_t)(f[k] & (CELLS - 1)),
                                         __float_as_uint(ww[k]));
            }
        }
    }
    if (blockIdx.x == 0 && threadIdx.x == 0) {
        for (int p = n & ~3; p < n; ++p) {
            int f = particle_flat(pos[3 * p], pos[3 * p + 1], pos[3 * p + 2]);
            if (f >= 0) {
                uint32_t slot = atomicAdd(&cur[f >> 14], 1u);
                pairs[slot] = make_uint2((uint32_t)(f & (CELLS - 1)),
                                         __float_as_uint(wgt[p]));
            }
        }
    }
}

__global__ __launch_bounds__(BT) void k4_seg(const uint2* __restrict__ pairs,
                                             const uint32_t* __restrict__ base,
                                             float* __restrict__ grid)
{
    __shared__ float acc[CELLS];
    for (int i = threadIdx.x; i < CELLS; i += BT) acc[i] = 0.0f;
    __syncthreads();

    int b = blockIdx.x;
    uint32_t s = base[b], e = base[b + 1];
    for (uint32_t i = s + threadIdx.x; i < e; i += BT) {
        uint2 p = pairs[i];
        atomicAdd(&acc[p.x], __uint_as_float(p.y));
    }
    __syncthreads();

    float4* out4 = (float4*)(grid + (size_t)b * CELLS);
    const float4* a4 = (const float4*)acc;
    for (int i = threadIdx.x; i < CELLS / 4; i += BT) out4[i] = a4[i];
}

__global__ __launch_bounds__(256) void forcegrid_scatter_atomic(
    const float* __restrict__ pos, const float* __restrict__ wgt,
    float* __restrict__ grid, int n)
{
    int t = blockIdx.x * blockDim.x + threadIdx.x;
    long long bse = (long long)t * 4;
    if (bse >= n) return;
    const float4* p4 = (const float4*)pos;
    float4 a = p4[(size_t)t * 3 + 0];
    float4 b = p4[(size_t)t * 3 + 1];
    float4 c = p4[(size_t)t * 3 + 2];
    float4 w = ((const float4*)wgt)[t];
    int   f[4]  = { particle_flat(a.x, a.y, a.z), particle_flat(a.w, b.x, b.y),
                    particle_flat(b.z, b.w, c.x), particle_flat(c.y, c.z, c.w) };
    float ww[4] = { w.x, w.y, w.z, w.w };
#pragma unroll
    for (int k = 0; k < 4; ++k) {
        if (bse + k >= n) break;
        if (f[k] >= 0) atomicAdd(&grid[f[k]], ww[k]);
    }
}

extern "C" void kernel_launch(void* const* d_in, const int* in_sizes, int n_in,
                              void* d_out, int out_size, void* d_ws, size_t ws_size,
                              hipStream_t stream)
{
    const float* pos = (const float*)d_in[0];   // [N,3]
    const float* wgt = (const float*)d_in[1];   // [N]
    float* grid = (float*)d_out;                // [256^3]
    int n = in_sizes[0] / 3;                    // 10,000,000

    // --- tier 1: fixed-segment pipeline (~153 MB ws) ------------------------
    size_t o1 = 0;
    uint2*    pairs1 = (uint2*)d_ws;                     o1 += (size_t)SB * NB * CAP * sizeof(uint2);
    uint32_t* cnt    = (uint32_t*)((char*)d_ws + o1);    o1 += (size_t)SB * NB * 4;
    uint2*    side   = (uint2*)((char*)d_ws + o1);       o1 += (size_t)SIDE_CAP * sizeof(uint2);
    uint32_t* side_n = (uint32_t*)((char*)d_ws + o1);    o1 += 64;

    if (ws_size >= o1 && n >= 4) {
        k0_init  <<<1,  64, 0, stream>>>(side_n);
        k3_direct<<<NB, BT, 0, stream>>>(pos, wgt, pairs1, cnt, side, side_n, n);
        k4_direct<<<SB, BT, 0, stream>>>(pairs1, cnt, side, side_n, grid);
        return;
    }

    // --- tier 2: hist + scans + direct scatter (~82 MB ws) ------------------
    size_t o2 = 0;
    uint2*    pairs2  = (uint2*)d_ws;                    o2 += (size_t)n * sizeof(uint2);
    uint32_t* hist2   = (uint32_t*)((char*)d_ws + o2);   o2 += (size_t)NB * SB * 4;
    uint32_t* offs2   = (uint32_t*)((char*)d_ws + o2);   o2 += (size_t)NB * SB * 4;
    uint32_t* totals2 = (uint32_t*)((char*)d_ws + o2);   o2 += (size_t)SB * 4;
    uint32_t* base2   = (uint32_t*)((char*)d_ws + o2);   o2 += (size_t)(SB + 1) * 4;

    if (ws_size >= o2) {
        k1_hist    <<<NB,       BT,  0, stream>>>(pos, hist2, n);
        k2a_colscan<<<SB / 128, 128, 0, stream>>>(hist2, offs2, totals2);
        k2b_scan   <<<1,        256, 0, stream>>>(totals2, base2);
        k3_scatter <<<NB,       BT,  0, stream>>>(pos, wgt, offs2, base2, pairs2, n);
        k4_seg     <<<SB,       BT,  0, stream>>>(pairs2, base2, grid);
    } else {
        (void)hipMemsetAsync(grid, 0, (size_t)out_size * sizeof(float), stream);
        int groups = (n + 3) / 4;
        forcegrid_scatter_atomic<<<(groups + 255) / 256, 256, 0, stream>>>(pos, wgt, grid, n);
    }
}

// Round 6
// 297.261 us; speedup vs baseline: 1.2537x; 1.2537x over previous
//
#include <hip/hip_runtime.h>
#include <stdint.h>

// ForceGrid: 10M weighted particles -> 256^3 float grid.
//
// Round-11 structure (2 real passes; latency-hidden chunk allocation):
//   k0_init   : gcur[bin] = bin*C; side_n = 0.                (tiny)
//   k3_direct : single pass over particles. LDS ring-stage per superbin
//               (1024 bins x 16-deep); flush aligned 8-pair (64B) chunks via
//               worklist (8 lanes/chunk -> coalesced 64B line, the shape
//               round-5 proved essential). ROUND-11: each bin's owner thread
//               CACHES its next dst in a register; flush consumes the cached
//               dst with NO wait and issues the refill atomicAdd(&gcur,8)
//               whose result is needed >=1 tile later -> atomic round-trip
//               latency hides under stage/copy/barriers. Epilogue consumes
//               the final pre-allocated chunk per bin (partial data
//               zero-padded to a full 64B line; (cell0,+0.0f) = no-op).
//               Cap overflow -> side-list, NO rollback (k4 clamps).
//   k4_direct : one block per superbin, 64KB LDS accumulate, dwordx4 NT
//               pair loads (all chunks full), side replay, NT store.
//
// Evidence trail: round-5 (owner-thread 16B stores) doubled WRITE_SIZE ->
// per-8-lane 64B worklist copy is load-bearing. Round-4 (prefetch, lgkm-only
// barriers) was neutral -> load latency wasn't the wall. Remaining exposed
// latency: the build phase's gcur atomic RESULT dependency. This round hides
// exactly that.
//
// Numerics (bit-exact index math vs the XLA-folded reference; DO NOT change):
//   fi = fl32((p + 10.0f) * 12.75f)   // 12.75f == fl32(1/fl32(20/255))
//   i  = (int32)fl32(fi + 0.5f)       // trunc toward zero, NO FMA contraction

constexpr int GRID_N = 256;
constexpr int SB     = 1024;    // superbins; superbin = flat >> 14
constexpr int CELLS  = 16384;   // cells per superbin (64KB LDS in K4)
constexpr int NB     = 256;     // blocks for the scatter pass (1/CU)
constexpr int BT     = 1024;    // threads per block (== SB: thread owns bin)
constexpr int RING   = 16;      // staged pairs per bin (power of 2)
constexpr int RSTR   = 17;      // ring stride in uint2 (LDS bank spread)
constexpr uint32_t SIDE_CAP = 262144;  // global overflow records (2MB)

typedef unsigned int u32x4 __attribute__((ext_vector_type(4)));
typedef float        f32x4 __attribute__((ext_vector_type(4)));

// Barrier with LDS-only drain: global loads/stores/atomics stay in flight.
#define BAR_LGKM() do { \
    asm volatile("s_waitcnt lgkmcnt(0)" ::: "memory"); \
    __builtin_amdgcn_s_barrier(); \
} while (0)

__device__ __forceinline__ int particle_flat(float px, float py, float pz) {
#pragma clang fp contract(off)
    float fix = (px + 10.0f) * 12.75f;
    float fiy = (py + 10.0f) * 12.75f;
    float fiz = (pz + 10.0f) * 12.75f;
    int ix = (int)(fix + 0.5f);
    int iy = (int)(fiy + 0.5f);
    int iz = (int)(fiz + 0.5f);
    bool in = (ix >= 0) & (ix < GRID_N) &
              (iy >= 0) & (iy < GRID_N) &
              (iz >= 0) & (iz < GRID_N);
    return in ? ((ix << 16) | (iy << 8) | iz) : -1;
}

// ---- k0: init allocation cursors --------------------------------------------
__global__ __launch_bounds__(1024) void k0_init(uint32_t* __restrict__ gcur,
                                                uint32_t* __restrict__ side_n,
                                                uint32_t C)
{
    int t = blockIdx.x * blockDim.x + threadIdx.x;
    if (t < SB) gcur[t] = (uint32_t)t * C;
    if (t == 0) *side_n = 0;
}

// ---- k3: staged scatter, worklist copy, latency-hidden allocation -----------
__global__ __launch_bounds__(BT, 1) void k3_direct(
    const float* __restrict__ pos, const float* __restrict__ wgt,
    uint32_t* __restrict__ gcur, uint2* __restrict__ pairs,
    uint2* __restrict__ side, uint32_t* __restrict__ side_n,
    uint32_t C, int n)
{
    __shared__ uint2    stg[SB][RSTR];     // ring storage (slots 0..15 used)
    __shared__ uint32_t s_total[SB];       // arrival count per bin (LDS atomic)
    __shared__ uint32_t s_flushed[SB];     // flushed count per bin (mult. of 8)
    __shared__ uint32_t s_wl[SB];          // worklist: (bin<<4) | (ringoff&15)
    __shared__ uint32_t s_wldst[SB];       // worklist: global dst pair-index
    __shared__ uint32_t s_wln;

    const int tid = threadIdx.x;
    const int blk = blockIdx.x;

    s_total[tid]   = 0;
    s_flushed[tid] = 0;
    if (tid == 0) s_wln = 0;

    // pre-allocate this bin's first chunk; result not needed until the
    // first flush (>= 1 tile away) -> latency hidden.
    uint32_t dst_cached = atomicAdd(&gcur[tid], 8u);
    const uint32_t capend = (uint32_t)(tid + 1) * C;
    __syncthreads();

    const float4* p4 = (const float4*)pos;
    const float4* w4 = (const float4*)wgt;
    int ngroups = n >> 2;
    int G = NB * BT;
    int iters = (ngroups + G - 1) / G;     // uniform across all threads/blocks

    // tile-0 load
    int g = blk * BT + tid;
    bool valid = g < ngroups;
    float4 a = {}, b = {}, c = {}, w = {};
    if (valid) {
        a = p4[(size_t)g * 3 + 0];
        b = p4[(size_t)g * 3 + 1];
        c = p4[(size_t)g * 3 + 2];
        w = w4[g];
    }

    for (int it = 0; it < iters; ++it) {
        if (tid == 0) s_wln = 0;           // prev copy done at loop-end barrier

        // ---- prefetch next tile into registers ----
        int gn = g + G;
        bool v2 = (it + 1 < iters) && (gn < ngroups);
        float4 a2 = {}, b2 = {}, c2 = {}, w2 = {};
        if (v2) {
            a2 = p4[(size_t)gn * 3 + 0];
            b2 = p4[(size_t)gn * 3 + 1];
            c2 = p4[(size_t)gn * 3 + 2];
            w2 = w4[gn];
        }

        // ---- stage current tile ----
        if (valid) {
            int   f[4]  = { particle_flat(a.x, a.y, a.z), particle_flat(a.w, b.x, b.y),
                            particle_flat(b.z, b.w, c.x), particle_flat(c.y, c.z, c.w) };
            float ww[4] = { w.x, w.y, w.z, w.w };
#pragma unroll
            for (int k = 0; k < 4; ++k) {
                int fk = f[k];
                if (fk >= 0) {
                    uint32_t bin  = (uint32_t)fk >> 14;
                    uint32_t slot = atomicAdd(&s_total[bin], 1u);
                    if (slot - s_flushed[bin] < (uint32_t)RING) {
                        stg[bin][slot & (RING - 1)] =
                            make_uint2((uint32_t)fk & (CELLS - 1), __float_as_uint(ww[k]));
                    } else {
                        // ring full: give the slot back (keeps staged slots dense),
                        // park the record in the global side-list.
                        atomicSub(&s_total[bin], 1u);
                        uint32_t si = atomicAdd(side_n, 1u);
                        if (si < SIDE_CAP)
                            side[si] = make_uint2((uint32_t)fk, __float_as_uint(ww[k]));
                    }
                }
            }
        }
        BAR_LGKM();
        // ---- build: consume CACHED dst (no wait), refill for next time ----
        {
            uint32_t p = s_total[tid] - s_flushed[tid];   // <= 16
            if (p >= 8u) {
                uint32_t o = s_flushed[tid];
                if (dst_cached < capend) {
                    uint32_t wi = atomicAdd(&s_wln, 1u);
                    s_wl[wi]    = ((uint32_t)tid << 4) | (o & (RING - 1));
                    s_wldst[wi] = dst_cached;
                } else {
                    // segment exhausted (uniform inputs: never): chunk -> side
                    for (int j = 0; j < 8; ++j) {
                        uint2 v = stg[tid][(o + j) & (RING - 1)];
                        uint32_t si = atomicAdd(side_n, 1u);
                        if (si < SIDE_CAP)
                            side[si] = make_uint2(((uint32_t)tid << 14) | v.x, v.y);
                    }
                }
                s_flushed[tid] = o + 8u;
                // refill: result consumed >= 1 tile later -> latency hidden
                dst_cached = atomicAdd(&gcur[tid], 8u);
            }
        }
        BAR_LGKM();
        // ---- copy: 8 lanes per chunk -> one dense, aligned 64B NT line ----
        {
            uint32_t m = s_wln;
            for (uint32_t j = tid; j < m * 8u; j += BT) {
                uint32_t e = s_wl[j >> 3];
                uint2 v = stg[e >> 4][((e & (RING - 1)) + (j & 7u)) & (RING - 1)];
                uint64_t v64 = (uint64_t)v.x | ((uint64_t)v.y << 32);
                __builtin_nontemporal_store(v64,
                    (uint64_t*)&pairs[(size_t)s_wldst[j >> 3] + (j & 7u)]);
            }
        }
        BAR_LGKM();

        a = a2; b = b2; c = c2; w = w2; valid = v2; g = gn;
    }

    // global tail (n % 4 particles): straight to side-list, block 0 only
    if (blk == 0 && tid == 0) {
        for (int p = n & ~3; p < n; ++p) {
            int f = particle_flat(pos[3 * p], pos[3 * p + 1], pos[3 * p + 2]);
            if (f >= 0) {
                uint32_t si = atomicAdd(side_n, 1u);
                if (si < SIDE_CAP)
                    side[si] = make_uint2((uint32_t)f, __float_as_uint(wgt[p]));
            }
        }
    }

    // ---- epilogue: consume each bin's one outstanding chunk -----------------
    // pending in [0,8]; zero-pad to a full chunk ((cell0,+0.0f) no-ops), then
    // one cooperative worklist copy round (1024 chunks max, s_wl holds SB).
    if (tid == 0) s_wln = 0;
    __syncthreads();
    {
        uint32_t t_ = s_total[tid];
        uint32_t fl = s_flushed[tid];
        uint32_t pending = t_ - fl;                      // 0..8
        if (dst_cached < capend) {
            for (uint32_t j = pending; j < 8u; ++j)
                stg[tid][(fl + j) & (RING - 1)] = make_uint2(0u, 0u);
            uint32_t wi = atomicAdd(&s_wln, 1u);
            s_wl[wi]    = ((uint32_t)tid << 4) | (fl & (RING - 1));
            s_wldst[wi] = dst_cached;
        } else if (pending) {
            for (uint32_t j = 0; j < pending; ++j) {
                uint2 v = stg[tid][(fl + j) & (RING - 1)];
                uint32_t si = atomicAdd(side_n, 1u);
                if (si < SIDE_CAP)
                    side[si] = make_uint2(((uint32_t)tid << 14) | v.x, v.y);
            }
        }
    }
    __syncthreads();
    {
        uint32_t m = s_wln;
        for (uint32_t j = tid; j < m * 8u; j += BT) {
            uint32_t e = s_wl[j >> 3];
            uint2 v = stg[e >> 4][((e & (RING - 1)) + (j & 7u)) & (RING - 1)];
            uint64_t v64 = (uint64_t)v.x | ((uint64_t)v.y << 32);
            __builtin_nontemporal_store(v64,
                (uint64_t*)&pairs[(size_t)s_wldst[j >> 3] + (j & 7u)]);
        }
    }
}

// ---- k4: one block per superbin — 64KB LDS accumulate, dwordx4 NT loads -----
__global__ __launch_bounds__(BT) void k4_direct(const uint2* __restrict__ pairs,
                                                const uint32_t* __restrict__ gcur,
                                                const uint2* __restrict__ side,
                                                const uint32_t* __restrict__ side_n,
                                                uint32_t C,
                                                float* __restrict__ grid)
{
    __shared__ float acc[CELLS];   // 64KB — 2 blocks/CU
    for (int i = threadIdx.x; i < CELLS; i += BT) acc[i] = 0.0f;
    __syncthreads();

    int b = blockIdx.x;
    uint32_t s = (uint32_t)b * C;
    uint32_t e = gcur[b];
    uint32_t cap = (uint32_t)(b + 1) * C;
    if (e > cap) e = cap;                  // over-allocations went to side-list
    // [s,e) is whole 8-pair chunks, 64B-aligned -> dwordx4 exact
    const u32x4* pp = (const u32x4*)(pairs + s);
    uint32_t m = (e - s) >> 1;             // # of u32x4 (2 pairs each)
    for (uint32_t i = threadIdx.x; i < m; i += BT) {
        u32x4 v = __builtin_nontemporal_load(&pp[i]);
        atomicAdd(&acc[v.x & (CELLS - 1)], __uint_as_float(v.y));
        atomicAdd(&acc[v.z & (CELLS - 1)], __uint_as_float(v.w));
    }
    // side-list replay (normally small; each block filters its own; side
    // buffer is L2/L3-resident across the 1024 re-reads)
    uint32_t ns = *side_n;
    if (ns > SIDE_CAP) ns = SIDE_CAP;
    for (uint32_t i = threadIdx.x; i < ns; i += BT) {
        uint2 sv = side[i];
        if ((int)(sv.x >> 14) == b)
            atomicAdd(&acc[sv.x & (CELLS - 1)], __uint_as_float(sv.y));
    }
    __syncthreads();

    f32x4* out4 = (f32x4*)(grid + (size_t)b * CELLS);
    const f32x4* a4 = (const f32x4*)acc;
    for (int i = threadIdx.x; i < CELLS / 4; i += BT)
        __builtin_nontemporal_store(a4[i], &out4[i]);
}

// ============================================================================
// tier-2 fallback: hist + scans + direct scatter (~82 MB ws)
// ============================================================================
__global__ __launch_bounds__(BT) void k1_hist(const float* __restrict__ pos,
                                              uint32_t* __restrict__ hist,
                                              int n)
{
    __shared__ uint32_t h[SB];
    for (int i = threadIdx.x; i < SB; i += BT) h[i] = 0;
    __syncthreads();

    const float4* p4 = (const float4*)pos;
    int ngroups = n >> 2;
    int G = gridDim.x * BT;
    for (int g = blockIdx.x * BT + threadIdx.x; g < ngroups; g += G) {
        float4 a = p4[(size_t)g * 3 + 0];
        float4 b = p4[(size_t)g * 3 + 1];
        float4 c = p4[(size_t)g * 3 + 2];
        int f0 = particle_flat(a.x, a.y, a.z);
        int f1 = particle_flat(a.w, b.x, b.y);
        int f2 = particle_flat(b.z, b.w, c.x);
        int f3 = particle_flat(c.y, c.z, c.w);
        if (f0 >= 0) atomicAdd(&h[f0 >> 14], 1u);
        if (f1 >= 0) atomicAdd(&h[f1 >> 14], 1u);
        if (f2 >= 0) atomicAdd(&h[f2 >> 14], 1u);
        if (f3 >= 0) atomicAdd(&h[f3 >> 14], 1u);
    }
    if (blockIdx.x == 0 && threadIdx.x == 0) {
        for (int p = n & ~3; p < n; ++p) {
            int f = particle_flat(pos[3 * p], pos[3 * p + 1], pos[3 * p + 2]);
            if (f >= 0) atomicAdd(&h[f >> 14], 1u);
        }
    }
    __syncthreads();
    uint32_t* out = hist + (size_t)blockIdx.x * SB;
    for (int i = threadIdx.x; i < SB; i += BT) out[i] = h[i];
}

__global__ __launch_bounds__(128) void k2a_colscan(const uint32_t* __restrict__ hist,
                                                   uint32_t* __restrict__ offs,
                                                   uint32_t* __restrict__ totals)
{
    int b = blockIdx.x * 128 + threadIdx.x;
    uint32_t run = 0;
    for (int blk = 0; blk < NB; blk += 8) {
        uint32_t v[8];
#pragma unroll
        for (int j = 0; j < 8; ++j)
            v[j] = hist[(size_t)(blk + j) * SB + b];
#pragma unroll
        for (int j = 0; j < 8; ++j) {
            offs[(size_t)(blk + j) * SB + b] = run;
            run += v[j];
        }
    }
    totals[b] = run;
}

__global__ __launch_bounds__(256) void k2b_scan(const uint32_t* __restrict__ totals,
                                                uint32_t* __restrict__ base)
{
    __shared__ uint32_t part[256];
    int t = threadIdx.x;
    uint32_t local[4];
    uint32_t s = 0;
#pragma unroll
    for (int j = 0; j < 4; ++j) { local[j] = totals[t * 4 + j]; s += local[j]; }
    part[t] = s;
    __syncthreads();
    if (t == 0) {
        uint32_t run = 0;
        for (int i = 0; i < 256; ++i) { uint32_t tmp = part[i]; part[i] = run; run += tmp; }
    }
    __syncthreads();
    uint32_t run = part[t];
#pragma unroll
    for (int j = 0; j < 4; ++j) { base[t * 4 + j] = run; run += local[j]; }
    if (t == 255) base[SB] = run;
}

__global__ __launch_bounds__(BT) void k3_scatter(const float* __restrict__ pos,
                                                 const float* __restrict__ wgt,
                                                 const uint32_t* __restrict__ offs,
                                                 const uint32_t* __restrict__ base,
                                                 uint2* __restrict__ pairs,
                                                 int n)
{
    __shared__ uint32_t cur[SB];
    for (int i = threadIdx.x; i < SB; i += BT)
        cur[i] = base[i] + offs[(size_t)blockIdx.x * SB + i];
    __syncthreads();

    const float4* p4 = (const float4*)pos;
    const float4* w4 = (const float4*)wgt;
    int ngroups = n >> 2;
    int G = gridDim.x * BT;
    for (int g = blockIdx.x * BT + threadIdx.x; g < ngroups; g += G) {
        float4 a = p4[(size_t)g * 3 + 0];
        float4 b = p4[(size_t)g * 3 + 1];
        float4 c = p4[(size_t)g * 3 + 2];
        float4 w = w4[g];
        int   f[4]  = { particle_flat(a.x, a.y, a.z), particle_flat(a.w, b.x, b.y),
                        particle_flat(b.z, b.w, c.x), particle_flat(c.y, c.z, c.w) };
        float ww[4] = { w.x, w.y, w.z, w.w };
#pragma unroll
        for (int k = 0; k < 4; ++k) {
            if (f[k] >= 0) {
                uint32_t slot = atomicAdd(&cur[f[k] >> 14], 1u);
                pairs[slot] = make_uint2((uint32_t)(f[k] & (CELLS - 1)),
                                         __float_as_uint(ww[k]));
            }
        }
    }
    if (blockIdx.x == 0 && threadIdx.x == 0) {
        for (int p = n & ~3; p < n; ++p) {
            int f = particle_flat(pos[3 * p], pos[3 * p + 1], pos[3 * p + 2]);
            if (f >= 0) {
                uint32_t slot = atomicAdd(&cur[f >> 14], 1u);
                pairs[slot] = make_uint2((uint32_t)(f & (CELLS - 1)),
                                         __float_as_uint(wgt[p]));
            }
        }
    }
}

__global__ __launch_bounds__(BT) void k4_seg(const uint2* __restrict__ pairs,
                                             const uint32_t* __restrict__ base,
                                             float* __restrict__ grid)
{
    __shared__ float acc[CELLS];
    for (int i = threadIdx.x; i < CELLS; i += BT) acc[i] = 0.0f;
    __syncthreads();

    int b = blockIdx.x;
    uint32_t s = base[b], e = base[b + 1];
    for (uint32_t i = s + threadIdx.x; i < e; i += BT) {
        uint2 p = pairs[i];
        atomicAdd(&acc[p.x], __uint_as_float(p.y));
    }
    __syncthreads();

    float4* out4 = (float4*)(grid + (size_t)b * CELLS);
    const float4* a4 = (const float4*)acc;
    for (int i = threadIdx.x; i < CELLS / 4; i += BT) out4[i] = a4[i];
}

__global__ __launch_bounds__(256) void forcegrid_scatter_atomic(
    const float* __restrict__ pos, const float* __restrict__ wgt,
    float* __restrict__ grid, int n)
{
    int t = blockIdx.x * blockDim.x + threadIdx.x;
    long long bse = (long long)t * 4;
    if (bse >= n) return;
    const float4* p4 = (const float4*)pos;
    float4 a = p4[(size_t)t * 3 + 0];
    float4 b = p4[(size_t)t * 3 + 1];
    float4 c = p4[(size_t)t * 3 + 2];
    float4 w = ((const float4*)wgt)[t];
    int   f[4]  = { particle_flat(a.x, a.y, a.z), particle_flat(a.w, b.x, b.y),
                    particle_flat(b.z, b.w, c.x), particle_flat(c.y, c.z, c.w) };
    float ww[4] = { w.x, w.y, w.z, w.w };
#pragma unroll
    for (int k = 0; k < 4; ++k) {
        if (bse + k >= n) break;
        if (f[k] >= 0) atomicAdd(&grid[f[k]], ww[k]);
    }
}

extern "C" void kernel_launch(void* const* d_in, const int* in_sizes, int n_in,
                              void* d_out, int out_size, void* d_ws, size_t ws_size,
                              hipStream_t stream)
{
    const float* pos = (const float*)d_in[0];   // [N,3]
    const float* wgt = (const float*)d_in[1];   // [N]
    float* grid = (float*)d_out;                // [256^3]
    int n = in_sizes[0] / 3;                    // 10,000,000

    // --- tier 1: latency-hidden allocation pipeline (~196 MB ws) ------------
    // per-bin capacity ~2.4x the mean bin load + init/epilogue chunk slack
    uint32_t C = ((2u * (uint32_t)(n / SB) + 4096u) + 7u) & ~7u;
    if (C < 1024u) C = 1024u;
    size_t o1 = 0;
    uint2*    pairs1 = (uint2*)d_ws;                     o1 += (size_t)SB * C * sizeof(uint2);
    uint2*    side   = (uint2*)((char*)d_ws + o1);       o1 += (size_t)SIDE_CAP * sizeof(uint2);
    uint32_t* gcur   = (uint32_t*)((char*)d_ws + o1);    o1 += (size_t)SB * 4;
    uint32_t* side_n = (uint32_t*)((char*)d_ws + o1);    o1 += 64;

    if (ws_size >= o1 && n >= 4) {
        k0_init  <<<1,  1024, 0, stream>>>(gcur, side_n, C);
        k3_direct<<<NB, BT,   0, stream>>>(pos, wgt, gcur, pairs1, side, side_n, C, n);
        k4_direct<<<SB, BT,   0, stream>>>(pairs1, gcur, side, side_n, C, grid);
        return;
    }

    // --- tier 2: hist + scans + direct scatter (~82 MB ws) ------------------
    size_t o2 = 0;
    uint2*    pairs2  = (uint2*)d_ws;                    o2 += (size_t)n * sizeof(uint2);
    uint32_t* hist2   = (uint32_t*)((char*)d_ws + o2);   o2 += (size_t)NB * SB * 4;
    uint32_t* offs2   = (uint32_t*)((char*)d_ws + o2);   o2 += (size_t)NB * SB * 4;
    uint32_t* totals2 = (uint32_t*)((char*)d_ws + o2);   o2 += (size_t)SB * 4;
    uint32_t* base2   = (uint32_t*)((char*)d_ws + o2);   o2 += (size_t)(SB + 1) * 4;

    if (ws_size >= o2) {
        k1_hist    <<<NB,       BT,  0, stream>>>(pos, hist2, n);
        k2a_colscan<<<SB / 128, 128, 0, stream>>>(hist2, offs2, totals2);
        k2b_scan   <<<1,        256, 0, stream>>>(totals2, base2);
        k3_scatter <<<NB,       BT,  0, stream>>>(pos, wgt, offs2, base2, pairs2, n);
        k4_seg     <<<SB,       BT,  0, stream>>>(pairs2, base2, grid);
    } else {
        (void)hipMemsetAsync(grid, 0, (size_t)out_size * sizeof(float), stream);
        int groups = (n + 3) / 4;
        forcegrid_scatter_atomic<<<(groups + 255) / 256, 256, 0, stream>>>(pos, wgt, grid, n);
    }
}